// Round 9
// baseline (145.931 us; speedup 1.0000x reference)
//
#include <hip/hip_runtime.h>
#include <hip/hip_fp16.h>

// Problem constants
#define BATCH 512
#define INF   512
#define OUTF  512
#define ND    128
#define WPART 262144          // IN_F*OUT_F
#define NSLOT 32              // P slots: 2 part x 16 i-chunks of 32 (bands folded)

typedef __attribute__((ext_vector_type(8))) _Float16 half8;
typedef __attribute__((ext_vector_type(2))) _Float16 half2v;
typedef __attribute__((ext_vector_type(4))) float    f32x4;

__device__ inline half8 cvt8(float4 a, float4 b) {
  half2v h0 = __builtin_bit_cast(half2v, __builtin_amdgcn_cvt_pkrtz(a.x, a.y));
  half2v h1 = __builtin_bit_cast(half2v, __builtin_amdgcn_cvt_pkrtz(a.z, a.w));
  half2v h2 = __builtin_bit_cast(half2v, __builtin_amdgcn_cvt_pkrtz(b.x, b.y));
  half2v h3 = __builtin_bit_cast(half2v, __builtin_amdgcn_cvt_pkrtz(b.z, b.w));
  half8 r = { h0[0], h0[1], h1[0], h1[1], h2[0], h2[1], h3[0], h3[1] };
  return r;
}

// -------------------------------------------------------------------------
// tail: TT[b,o] = sum_n hn[b,n] * (hW[WPART+o,n] + pW[WPART+o,n])
// -------------------------------------------------------------------------
__global__ void __launch_bounds__(256) tail_kernel(
    const float* __restrict__ hn, const float* __restrict__ hW,
    const float* __restrict__ pW, float* __restrict__ TT) {
  const int bt = blockIdx.x & 7;
  const int bg = blockIdx.x >> 3;
  __shared__ float wsum[64][132];
  __shared__ float hs[32][132];
  {
    int r = threadIdx.x >> 2, seg = threadIdx.x & 3;
    const float4* h4 = (const float4*)(hW + (((size_t)(WPART + bt*64 + r)) << 7) + seg*32);
    const float4* p4 = (const float4*)(pW + (((size_t)(WPART + bt*64 + r)) << 7) + seg*32);
    #pragma unroll
    for (int qq = 0; qq < 8; ++qq) {
      float4 a = h4[qq], b = p4[qq];
      float* d = &wsum[r][seg*32 + qq*4];
      d[0]=a.x+b.x; d[1]=a.y+b.y; d[2]=a.z+b.z; d[3]=a.w+b.w;
    }
    int bb = threadIdx.x >> 3, ch = threadIdx.x & 7;
    const float4* hh = (const float4*)(hn + (((size_t)(bg*32 + bb)) << 7) + ch*16);
    #pragma unroll
    for (int qq = 0; qq < 4; ++qq) {
      float4 a = hh[qq];
      float* d = &hs[bb][ch*16 + qq*4];
      d[0]=a.x; d[1]=a.y; d[2]=a.z; d[3]=a.w;
    }
  }
  __syncthreads();
  const int ol = threadIdx.x & 63, b0 = (threadIdx.x >> 6) * 8;
  float a[8] = {};
  for (int n = 0; n < 128; n += 4) {
    float4 wv = *(const float4*)&wsum[ol][n];
    #pragma unroll
    for (int r = 0; r < 8; ++r) {
      float4 hv = *(const float4*)&hs[b0 + r][n];
      a[r] += hv.x*wv.x + hv.y*wv.y + hv.z*wv.z + hv.w*wv.w;
    }
  }
  #pragma unroll
  for (int r = 0; r < 8; ++r)
    TT[(((size_t)(bg*32 + b0 + r)) << 9) + bt*64 + ol] = a[r];
}

// -------------------------------------------------------------------------
// GEMM.  Slot q = (part, i-chunk of 32).  16 global phases g = band*4 + pp;
// phase covers 8 i x 32 n (one band) = BK 256, 64 MFMA/wave between barriers.
// BM=512, BN=32, 8 waves (4M x 2N), wave tile 128x16, acc[8] f32x4.
//  - xh: [pp(4)][b(512)][8 i] fp16 LDS (32KB), staged once.  A lane's 8 i's
//    = ONE b128, 16 lanes consecutive 16B -> conflict-free (R7 law).
//  - W: [il(8)][j(4)][o(32)] half8 LDS dbuf 2x16KB; reg-staged 2 phases
//    ahead (4 float4/thread), cvt+write 1 ahead (T14); lane-consecutive
//    b128 reads/writes, no XOR.  1 lgkmcnt(0)+barrier per phase (T4).
//  - hnf: 8 half8 regs, reloaded at band boundaries (3x, wave-uniform).
//  - A synthesized: af = hnf[m] * splat(hx[m][il]) via v_pk_mul_f16.
// Grid (32 slots, 16 n-tiles) = 512 blocks = 2/CU (LDS 64KB).
// -------------------------------------------------------------------------
__global__ void __launch_bounds__(512) gemm_kernel(
    const float* __restrict__ x, const float* __restrict__ px,
    const float* __restrict__ hn, const float* __restrict__ hW,
    const float* __restrict__ pW, float* __restrict__ P) {
  const int tid = threadIdx.x;
  const int lane = tid & 63, w = tid >> 6;
  const int l15 = lane & 15, j = lane >> 4;
  const int wm = w >> 1, wn = w & 1;        // 4 M-waves x 2 N-waves

  const int q  = blockIdx.x;
  const int n0 = blockIdx.y << 5;
  const int part = q >> 4;
  const int i0   = (q & 15) << 5;
  const float* srcW = part ? pW : hW;
  const float* srcX = part ? px : x;

  __shared__ half8 ldsW[2][1024];           // [buf][il*128 + jj*32 + o] 16KB ea
  __shared__ half8 xh[4][512];              // [pp][b] = 8 i fp16, 32KB

  f32x4 acc[8] = {};

  // ---- stage xh once ----
  {
    const int rsub = tid >> 3, ch = tid & 7;       // ch = float4 idx over 32 i
    const int pp = ch >> 1, sub = ch & 1;
    #pragma unroll
    for (int r = 0; r < 8; ++r) {
      int row = r * 64 + rsub;
      float4 v = *(const float4*)(srcX + ((size_t)row << 9) + i0 + ch * 4);
      unsigned ua = __builtin_bit_cast(unsigned, __builtin_amdgcn_cvt_pkrtz(v.x, v.y));
      unsigned ub = __builtin_bit_cast(unsigned, __builtin_amdgcn_cvt_pkrtz(v.z, v.w));
      uint2 uu; uu.x = ua; uu.y = ub;
      *(uint2*)((char*)xh + pp * 8192 + row * 16 + sub * 8) = uu;
    }
  }

  // ---- W staging coords: thread -> (il, o, half-of-32n) ----
  const int il_s = tid >> 6;                // 0..7
  const int o_s  = (tid >> 1) & 31;
  const int hf_s = tid & 1;

  auto loadW = [&](int g, float4* rw) {
    int i = i0 + ((g & 3) << 3) + il_s;
    const float4* p4 = (const float4*)(srcW +
        (((size_t)((i << 9) + n0 + o_s)) << 7) + ((g >> 2) << 5) + (hf_s << 4));
    rw[0] = p4[0]; rw[1] = p4[1]; rw[2] = p4[2]; rw[3] = p4[3];
  };
  auto writeW = [&](int buf, const float4* rw) {
    char* base = (char*)ldsW + buf * 16384 + il_s * 2048 + hf_s * 1024 + o_s * 16;
    *(half8*)base         = cvt8(rw[0], rw[1]);
    *(half8*)(base + 512) = cvt8(rw[2], rw[3]);
  };

  half8 hnf[8];
  auto loadHnf = [&](int band) {
    #pragma unroll
    for (int m = 0; m < 8; ++m) {
      int row = wm * 128 + m * 16 + l15;
      const float4* hp = (const float4*)(hn + ((size_t)row << 7) + (band << 5) + (j << 3));
      hnf[m] = cvt8(hp[0], hp[1]);
    }
  };

  auto compute = [&](int buf, int g) {
    const char* WB = (const char*)ldsW + buf * 16384;
    const int pp = g & 3;
    half8 bfv[8], hx[8];
    #pragma unroll
    for (int il = 0; il < 8; ++il)
      bfv[il] = *(const half8*)(WB + il * 2048 + j * 512 + ((wn << 4) + l15) * 16);
    #pragma unroll
    for (int m = 0; m < 8; ++m) {
      int row = wm * 128 + m * 16 + l15;
      hx[m] = *(const half8*)((const char*)xh + pp * 8192 + row * 16);
    }
    __builtin_amdgcn_s_setprio(1);
    #pragma unroll
    for (int il = 0; il < 8; ++il) {
      #pragma unroll
      for (int m = 0; m < 8; ++m) {
        _Float16 xs = hx[m][il];
        half8 xb = { xs, xs, xs, xs, xs, xs, xs, xs };
        acc[m] = __builtin_amdgcn_mfma_f32_16x16x32_f16(
            hnf[m] * xb, bfv[il], acc[m], 0, 0, 0);
      }
    }
    __builtin_amdgcn_s_setprio(0);
  };

  // ---- prologue ----
  float4 rwA[4], rwB[4];
  loadHnf(0);
  loadW(0, rwA);
  loadW(1, rwB);
  writeW(0, rwA);                           // auto-vmcnt retires rwA only
  asm volatile("s_waitcnt lgkmcnt(0)" ::: "memory");
  __builtin_amdgcn_s_barrier();

  // ---- 16 phases, 2 per iteration; W loads stay in flight across barriers
  #pragma unroll 1
  for (int g = 0; g < 16; g += 2) {
    if (g > 0 && (g & 3) == 0) loadHnf(g >> 2);   // band boundary (g=4,8,12)
    if (g + 2 < 16) loadW(g + 2, rwA);
    compute(0, g);
    writeW(1, rwB);
    asm volatile("s_waitcnt lgkmcnt(0)" ::: "memory");
    __builtin_amdgcn_s_barrier();

    if (g + 3 < 16) loadW(g + 3, rwB);
    compute(1, g + 1);
    if (g + 2 < 16) writeW(0, rwA);
    asm volatile("s_waitcnt lgkmcnt(0)" ::: "memory");
    __builtin_amdgcn_s_barrier();
  }

  // ---- epilogue: C/D col=lane&15, row=(lane>>4)*4+e ----
  float* outp = P + ((size_t)q << 18);
  #pragma unroll
  for (int m = 0; m < 8; ++m) {
    int row = wm * 128 + m * 16 + (j << 2);
    int col = n0 + (wn << 4) + l15;
    float* op = outp + (size_t)row * OUTF + col;
    op[0]    = acc[m][0];
    op[512]  = acc[m][1];
    op[1024] = acc[m][2];
    op[1536] = acc[m][3];
  }
}

// -------------------------------------------------------------------------
// finish: out[b,o] = sum_k P[k][b][o] + TT[b,o]
//                  + sum_i x[b,i]*hb[i*512+o] + hb[WPART+o]
// -------------------------------------------------------------------------
__global__ void __launch_bounds__(256) finish_kernel(
    const float* __restrict__ P, const float* __restrict__ x,
    const float* __restrict__ hb, const float* __restrict__ TT,
    float* __restrict__ out) {
  const int o  = blockIdx.x * 256 + threadIdx.x;
  const int b0 = blockIdx.y * 2;
  __shared__ float xs[2][512];
  #pragma unroll
  for (int t = 0; t < 4; ++t) {
    int idx = threadIdx.x + t * 256;
    xs[idx >> 9][idx & 511] = x[((size_t)(b0 + (idx >> 9)) << 9) + (idx & 511)];
  }
  __syncthreads();

  const float bias = hb[WPART + o];
  float a0 = bias, a1 = bias;
  #pragma unroll 16
  for (int i = 0; i < 512; ++i) {
    float hv = hb[(i << 9) + o];
    a0 += xs[0][i] * hv;
    a1 += xs[1][i] * hv;
  }
  a0 += TT[((size_t)b0 << 9) + o];
  a1 += TT[((size_t)(b0 + 1) << 9) + o];

  const float* P0 = P + ((size_t)b0 << 9) + o;
  const float* P1 = P0 + 512;
  float t00 = 0, t01 = 0, t10 = 0, t11 = 0;
  #pragma unroll 4
  for (int k = 0; k < NSLOT; k += 2) {
    t00 += P0[(size_t)(k)     << 18];
    t01 += P0[(size_t)(k + 1) << 18];
    t10 += P1[(size_t)(k)     << 18];
    t11 += P1[(size_t)(k + 1) << 18];
  }
  out[((size_t)b0 << 9) + o]       = a0 + t00 + t01;
  out[((size_t)(b0 + 1) << 9) + o] = a1 + t10 + t11;
}

extern "C" void kernel_launch(void* const* d_in, const int* in_sizes, int n_in,
                              void* d_out, int out_size, void* d_ws, size_t ws_size,
                              hipStream_t stream) {
  const float* x  = (const float*)d_in[0];
  const float* px = (const float*)d_in[1];
  const float* hn = (const float*)d_in[2];
  const float* hW = (const float*)d_in[3];
  const float* hb = (const float*)d_in[4];
  const float* pW = (const float*)d_in[5];
  // d_in[6] = pb is all zeros
  float* out = (float*)d_out;
  float* TT  = (float*)d_ws;                    // 1 MB
  float* P   = TT + (1 << 18);                  // 32 x 1 MB

  tail_kernel<<<dim3(128), 256, 0, stream>>>(hn, hW, pW, TT);
  gemm_kernel<<<dim3(NSLOT, 16), dim3(512), 0, stream>>>(x, px, hn, hW, pW, P);
  finish_kernel<<<dim3(2, 256), dim3(256), 0, stream>>>(P, x, hb, TT, out);
}